// Round 10
// baseline (343640.161 us; speedup 1.0000x reference)
//
#include <hip/hip_runtime.h>
#include <hip/hip_bf16.h>

#define T_STEPS 8192
#define OBS 256
#define HID 2048
#define NOUT 256

#define NPART 32   // participating blocks (one XCD's worth of CUs)
#define NTHR 1024  // threads per scan block: 16 waves, wave owns 4 units

typedef unsigned long long u64;
typedef _Float16 half2v __attribute__((ext_vector_type(2)));
typedef __fp16 fp16x2 __attribute__((ext_vector_type(2)));

// ws layout:
//   [0, 64)        : ctrl  {u32 leader_lock, u32 chosen(bit31=pub), u32 cnt}
//   [4096, 20480)  : h_pair, 2 buffers x 1024 u64 {tag:u32, fp16x2 pair}
//   [65536, +32MB) : hidden, T x HID bf16
#define WS_CTRL_OFF 0
#define WS_HBUF_OFF 4096
#define WS_HIDDEN_OFF 65536

__global__ void gru_init_kernel(u64* h_pair, unsigned* ctrl) {
  const int t = blockIdx.x * blockDim.x + threadIdx.x;
  h_pair[t] = 0ull;  // 2048 u64: tags=0 (valid for step 0), values=0
  if (t < 3) ctrl[t] = 0u;
}

__device__ __forceinline__ half2v bc_h2(unsigned u) {
  union { unsigned u; half2v h; } c;
  c.u = u;
  return c.h;
}
__device__ __forceinline__ unsigned pk_rn(float lo, float hi) {
  union { half2v h; unsigned u; } c;
  c.h[0] = (_Float16)lo;  // RNE
  c.h[1] = (_Float16)hi;
  return c.u;
}
__device__ __forceinline__ unsigned pk_rtz(float lo, float hi) {
  union { fp16x2 h; unsigned u; } c;
  c.h = __builtin_amdgcn_cvt_pkrtz(lo, hi);
  return c.u;
}
__device__ __forceinline__ float fdot2f(unsigned a, unsigned b, float c) {
#if __has_builtin(__builtin_amdgcn_fdot2)
  return __builtin_amdgcn_fdot2(bc_h2(a), bc_h2(b), c, false);
#else
  const half2v ha = bc_h2(a), hb = bc_h2(b);
  return c + (float)ha[0] * (float)hb[0] + (float)ha[1] * (float)hb[1];
#endif
}

// Persistent scan on ONE XCD: 256 blocks launched; a leader picks its XCD;
// the 32 blocks there register (slots 0..31) and run; others exit (after a
// 250us fallback window that makes the scheme deadlock-proof even if
// XCC_ID reads garbage). Participant p owns units p*64..p*64+63; wave v owns
// units p*64+4v..+3 (12 weight rows, packed fp16, 240 VGPRs, asm-pinned).
// Exchange: 1024 u64 slots {step-tag, fp16x2}; thread tid polls slot tid.
// All exchange lines live in the chosen XCD's L2 -> visibility ~L2 latency
// instead of the ~2us cross-XCD coherence cycle measured in rounds 7-9.
__global__ __launch_bounds__(NTHR) void gru_scan_kernel(
    const float* __restrict__ ys, const float* __restrict__ wi,
    const float* __restrict__ wh, const float* __restrict__ b,
    const float* __restrict__ bn, __hip_bfloat16* __restrict__ hidden,
    u64* h_pair, unsigned* ctrl) {
  const int tid = threadIdx.x;
  const int wave = tid >> 6;
  const int lane = tid & 63;

  // x_lds oversized to >80KB total LDS => hardware cannot co-schedule two
  // blocks on one CU (belt-and-braces with the ~306 VGPR footprint).
  __shared__ __align__(16) unsigned hq_lds[2][HID / 2];  // 8KB
  __shared__ __align__(16) float x_lds[2][10240];        // 80KB (use [0..511])
  __shared__ unsigned pair_lds[2][32];
  __shared__ int s_p;

  // ---- registration: pick 32 blocks on one XCD (deadlock-proof) ----
  if (tid == 0) {
    unsigned xcc = 0;
    asm volatile("s_getreg_b32 %0, hwreg(20, 0, 32)" : "=s"(xcc));
    xcc &= 0xFu;
    if (atomicCAS(&ctrl[0], 0u, 1u) == 0u)
      __hip_atomic_store(&ctrl[1], 0x80000000u | xcc, __ATOMIC_RELAXED,
                         __HIP_MEMORY_SCOPE_AGENT);
    unsigned ch;
    do {
      ch = __hip_atomic_load(&ctrl[1], __ATOMIC_RELAXED,
                             __HIP_MEMORY_SCOPE_AGENT);
      if (!(ch >> 31)) __builtin_amdgcn_s_sleep(8);
    } while (!(ch >> 31));
    if ((ch & 0xFu) != xcc) {
      // fallback: wait 250us (100MHz realtime clock), then register anyway
      const u64 t0 = __builtin_amdgcn_s_memrealtime();
      while (__builtin_amdgcn_s_memrealtime() - t0 < 25000ull) {
        if (__hip_atomic_load(&ctrl[2], __ATOMIC_RELAXED,
                              __HIP_MEMORY_SCOPE_AGENT) >= NPART)
          break;
        __builtin_amdgcn_s_sleep(32);
      }
    }
    const unsigned slot = atomicAdd(&ctrl[2], 1u);
    s_p = (slot < NPART) ? (int)slot : -1;
  }
  __syncthreads();
  const int p = s_p;
  if (p < 0) return;

  // ---- one-time: stage 12 rows/wave of wh,wi as packed fp16 in VGPRs ----
  // Wave owns units base+4v+e (e=0..3); rows {u, H+u, 2H+u}; idx = e*3+g.
  const int base = p * 64;
  unsigned whp[12][16];
  unsigned wip[12][4];
#pragma unroll
  for (int e = 0; e < 4; ++e) {
#pragma unroll
    for (int g = 0; g < 3; ++g) {
      const int idx = e * 3 + g;
      const size_t R = (size_t)(g * HID + base + wave * 4 + e);
#pragma unroll
      for (int m = 0; m < 8; ++m) {
        const float4 q =
            *reinterpret_cast<const float4*>(wh + R * HID + m * 256 + lane * 4);
        whp[idx][2 * m] = pk_rn(q.x, q.y);
        whp[idx][2 * m + 1] = pk_rn(q.z, q.w);
      }
#pragma unroll
      for (int pp = 0; pp < 2; ++pp) {
        const float4 q =
            *reinterpret_cast<const float4*>(wi + R * 512 + pp * 256 + lane * 4);
        wip[idx][2 * pp] = pk_rn(q.x, q.y);
        wip[idx][2 * pp + 1] = pk_rn(q.z, q.w);
      }
    }
  }
#pragma unroll
  for (int r = 0; r < 12; ++r) {
#pragma unroll
    for (int m = 0; m < 16; ++m) asm volatile("" : "+v"(whp[r][m]));
#pragma unroll
    for (int q = 0; q < 4; ++q) asm volatile("" : "+v"(wip[r][q]));
  }

  // Gate constants for unit e = lane&3 of this wave.
  const int iu = base + wave * 4 + (lane & 3);
  const float b_r = b[iu];
  const float b_z = b[HID + iu];
  const float b_n = b[2 * HID + iu];
  const float bn_v = bn[iu];

  float h_own = 0.f;

#pragma unroll 1
  for (int s = 0; s < T_STEPS; ++s) {
    const int buf = s & 1;
    const u64* hp = h_pair + buf * (HID / 2);
    u64* hp_next = h_pair + (buf ^ 1) * (HID / 2);
    const unsigned tag = (unsigned)s;

    float y = 0.f;
    if (tid < 512) y = ys[(size_t)s * OBS + (tid & 255)];

    // ---- poll own slot: ONE u64 per thread ----
    u64 v = __hip_atomic_load(hp + tid, __ATOMIC_RELAXED,
                              __HIP_MEMORY_SCOPE_AGENT);
    while ((unsigned)(v >> 32) != tag) {
      __builtin_amdgcn_s_sleep(1);
      v = __hip_atomic_load(hp + tid, __ATOMIC_RELAXED,
                            __HIP_MEMORY_SCOPE_AGENT);
    }
    hq_lds[buf][tid] = (unsigned)v;
    if (tid < 512) {
      const bool good = (y == y);  // !isnan
      x_lds[buf][tid] = (tid < 256) ? (good ? y : 0.f) : (good ? 1.f : 0.f);
    }
    __syncthreads();  // sync1

    // ---- fragments ----
    unsigned hq[16], xq[4];
#pragma unroll
    for (int m = 0; m < 8; ++m) {
      const uint2 q =
          *reinterpret_cast<const uint2*>(&hq_lds[buf][m * 128 + lane * 2]);
      hq[2 * m] = q.x;
      hq[2 * m + 1] = q.y;
    }
#pragma unroll
    for (int pp = 0; pp < 2; ++pp) {
      const float4 q =
          *reinterpret_cast<const float4*>(&x_lds[buf][pp * 256 + lane * 4]);
      xq[2 * pp] = pk_rtz(q.x, q.y);
      xq[2 * pp + 1] = pk_rtz(q.z, q.w);
    }

    // ---- 16 accumulators: a[4e+{0:r,1:z,2:hn,3:in}] for units e=0..3 ----
    float a[16];
#pragma unroll
    for (int e = 0; e < 4; ++e) {
      float ar = 0.f, az = 0.f, ahn = 0.f, ain = 0.f;
      const int r0 = e * 3, r1 = e * 3 + 1, r2 = e * 3 + 2;
#pragma unroll
      for (int m = 0; m < 16; ++m) {
        ar = fdot2f(whp[r0][m], hq[m], ar);
        az = fdot2f(whp[r1][m], hq[m], az);
        ahn = fdot2f(whp[r2][m], hq[m], ahn);
      }
#pragma unroll
      for (int q = 0; q < 4; ++q) {
        ar = fdot2f(wip[r0][q], xq[q], ar);
        az = fdot2f(wip[r1][q], xq[q], az);
        ain = fdot2f(wip[r2][q], xq[q], ain);
      }
      a[4 * e] = ar;
      a[4 * e + 1] = az;
      a[4 * e + 2] = ahn;
      a[4 * e + 3] = ain;
    }

    // ---- combining butterfly: 16 sums in 15+2 shuffles ----
    // comp c=(c3c2c1c0) ends at lane&15 = c3 | c2<<1 | c1<<2 | c0<<3.
#pragma unroll
    for (int j = 0; j < 8; ++j) {
      const bool sel = (lane & 1) != 0;
      const float keep = sel ? a[j + 8] : a[j];
      const float send = sel ? a[j] : a[j + 8];
      a[j] = keep + __shfl_xor(send, 1, 64);
    }
#pragma unroll
    for (int j = 0; j < 4; ++j) {
      const bool sel = (lane & 2) != 0;
      const float keep = sel ? a[j + 4] : a[j];
      const float send = sel ? a[j] : a[j + 4];
      a[j] = keep + __shfl_xor(send, 2, 64);
    }
#pragma unroll
    for (int j = 0; j < 2; ++j) {
      const bool sel = (lane & 4) != 0;
      const float keep = sel ? a[j + 2] : a[j];
      const float send = sel ? a[j] : a[j + 2];
      a[j] = keep + __shfl_xor(send, 4, 64);
    }
    {
      const bool sel = (lane & 8) != 0;
      const float keep = sel ? a[1] : a[0];
      const float send = sel ? a[0] : a[1];
      a[0] = keep + __shfl_xor(send, 8, 64);
    }
    float redv = a[0];
    redv += __shfl_xor(redv, 16, 64);
    redv += __shfl_xor(redv, 32, 64);

    // gather: comp c=4e+part at lane (e>>1) + 2*(e&1) + 4*(part>>1) + 8*(part&1)
    const int e = lane & 3;
    const int bsrc = ((e & 1) << 1) | (e >> 1);
    const float d_r = __shfl(redv, bsrc, 64);
    const float d_z = __shfl(redv, bsrc + 8, 64);
    const float d_hn = __shfl(redv, bsrc + 4, 64);
    const float d_in = __shfl(redv, bsrc + 12, 64);

    // ---- gate math (valid everywhere; lanes 0..3 hold the real state) ----
    const float rg = 1.f / (1.f + expf(-(d_r + b_r)));
    const float zg = 1.f / (1.f + expf(-(d_z + b_z)));
    const float ng = tanhf(d_in + b_n + rg * (d_hn + bn_v));
    const float hnew = ng + zg * (h_own - ng);
    h_own = hnew;

    const float h_nb = __shfl_xor(hnew, 1, 64);  // partner unit's h
    if (lane < 4 && !(lane & 1)) {  // lanes 0,2: pairs (e0,e1),(e2,e3)
      pair_lds[buf][wave * 2 + (lane >> 1)] = pk_rtz(hnew, h_nb);
      const unsigned bfp =
          ((unsigned)__bfloat16_as_ushort(__float2bfloat16(h_nb)) << 16) |
          (unsigned)__bfloat16_as_ushort(__float2bfloat16(hnew));
      *reinterpret_cast<unsigned*>(
          &hidden[(size_t)s * HID + base + wave * 4 + lane]) = bfp;
    }
    __syncthreads();  // sync2

    // ---- publish: 32 tagged u64 (one 256B burst) ----
    if (tid < 32) {
      const u64 pv = ((u64)(tag + 1) << 32) | (u64)pair_lds[buf][tid];
      __hip_atomic_store(hp_next + p * 32 + tid, pv, __ATOMIC_RELAXED,
                         __HIP_MEMORY_SCOPE_AGENT);
    }
  }
}

// out[t][o] = bl[o] + sum_k hidden[t][k] * Wl[o][k]
__global__ __launch_bounds__(256) void out_gemm_kernel(
    const __hip_bfloat16* __restrict__ hidden, const float* __restrict__ Wl,
    const float* __restrict__ bl, float* __restrict__ out) {
  __shared__ float As[16][68];
  __shared__ float Bs[16][68];
  const int tid = threadIdx.x;
  const int bt = blockIdx.x * 64;
  const int bo = blockIdx.y * 64;
  const int tx = tid & 15;
  const int ty = tid >> 4;
  const int tA = tid >> 2;
  const int kq = (tid & 3) << 2;
  const unsigned short* hidu = reinterpret_cast<const unsigned short*>(hidden);

  float acc[4][4];
#pragma unroll
  for (int i = 0; i < 4; ++i)
#pragma unroll
    for (int j = 0; j < 4; ++j) acc[i][j] = 0.f;

  for (int k0 = 0; k0 < HID; k0 += 16) {
    const ushort4 av = *reinterpret_cast<const ushort4*>(
        hidu + (size_t)(bt + tA) * HID + k0 + kq);
    As[kq + 0][tA] = __uint_as_float((unsigned)av.x << 16);
    As[kq + 1][tA] = __uint_as_float((unsigned)av.y << 16);
    As[kq + 2][tA] = __uint_as_float((unsigned)av.z << 16);
    As[kq + 3][tA] = __uint_as_float((unsigned)av.w << 16);
    const float4 bv = *reinterpret_cast<const float4*>(
        Wl + (size_t)(bo + tA) * HID + k0 + kq);
    Bs[kq + 0][tA] = bv.x;
    Bs[kq + 1][tA] = bv.y;
    Bs[kq + 2][tA] = bv.z;
    Bs[kq + 3][tA] = bv.w;
    __syncthreads();
#pragma unroll
    for (int k = 0; k < 16; ++k) {
      const float4 a = *reinterpret_cast<const float4*>(&As[k][ty << 2]);
      const float4 bq = *reinterpret_cast<const float4*>(&Bs[k][tx << 2]);
      const float a4[4] = {a.x, a.y, a.z, a.w};
      const float b4[4] = {bq.x, bq.y, bq.z, bq.w};
#pragma unroll
      for (int i = 0; i < 4; ++i)
#pragma unroll
        for (int j = 0; j < 4; ++j) acc[i][j] += a4[i] * b4[j];
    }
    __syncthreads();
  }
#pragma unroll
  for (int i = 0; i < 4; ++i) {
    const int t = bt + (ty << 2) + i;
#pragma unroll
    for (int j = 0; j < 4; ++j) {
      const int o = bo + (tx << 2) + j;
      out[(size_t)t * NOUT + o] = acc[i][j] + bl[o];
    }
  }
}

extern "C" void kernel_launch(void* const* d_in, const int* in_sizes, int n_in,
                              void* d_out, int out_size, void* d_ws,
                              size_t ws_size, hipStream_t stream) {
  (void)in_sizes;
  (void)n_in;
  (void)out_size;
  (void)ws_size;
  // setup_inputs order: ts, ys, wi, wh, b, bn, Wl, bl (all f32)
  const float* ys = (const float*)d_in[1];
  const float* wi = (const float*)d_in[2];
  const float* wh = (const float*)d_in[3];
  const float* b = (const float*)d_in[4];
  const float* bn = (const float*)d_in[5];
  const float* Wl = (const float*)d_in[6];
  const float* bl = (const float*)d_in[7];
  float* out = (float*)d_out;

  unsigned* ctrl = (unsigned*)((char*)d_ws + WS_CTRL_OFF);
  u64* h_pair = (u64*)((char*)d_ws + WS_HBUF_OFF);
  __hip_bfloat16* hidden = (__hip_bfloat16*)((char*)d_ws + WS_HIDDEN_OFF);

  gru_init_kernel<<<8, 256, 0, stream>>>(h_pair, ctrl);

  gru_scan_kernel<<<dim3(256), dim3(NTHR), 0, stream>>>(ys, wi, wh, b, bn,
                                                        hidden, h_pair, ctrl);

  out_gemm_kernel<<<dim3(T_STEPS / 64, NOUT / 64), 256, 0, stream>>>(
      hidden, Wl, bl, out);
}

// Round 11
// 343424.170 us; speedup vs baseline: 1.0006x; 1.0006x over previous
//
#include <hip/hip_runtime.h>
#include <hip/hip_bf16.h>

#define T_STEPS 8192
#define OBS 256
#define HID 2048
#define NOUT 256

#define NPART 32   // participating blocks (one XCD's worth of CUs)
#define NTHR 1024  // threads per scan block: 16 waves, wave owns 4 units

typedef unsigned long long u64;
typedef _Float16 half2v __attribute__((ext_vector_type(2)));
typedef __fp16 fp16x2 __attribute__((ext_vector_type(2)));

// ws layout:
//   [0, 64)        : ctrl  {u32 leader_lock, u32 chosen(bit31=pub), u32 cnt}
//   [4096, 20480)  : h_pair, 2 buffers x 1024 u64 {tag:u32, fp16x2 pair}
//   [65536, +32MB) : hidden, T x HID bf16
#define WS_CTRL_OFF 0
#define WS_HBUF_OFF 4096
#define WS_HIDDEN_OFF 65536

__global__ void gru_init_kernel(u64* h_pair, unsigned* ctrl) {
  const int t = blockIdx.x * blockDim.x + threadIdx.x;
  h_pair[t] = 0ull;  // 2048 u64: tags=0 (valid for step 0), values=0
  if (t < 3) ctrl[t] = 0u;
}

__device__ __forceinline__ half2v bc_h2(unsigned u) {
  union { unsigned u; half2v h; } c;
  c.u = u;
  return c.h;
}
__device__ __forceinline__ unsigned pk_rn(float lo, float hi) {
  union { half2v h; unsigned u; } c;
  c.h[0] = (_Float16)lo;  // RNE
  c.h[1] = (_Float16)hi;
  return c.u;
}
__device__ __forceinline__ unsigned pk_rtz(float lo, float hi) {
  union { fp16x2 h; unsigned u; } c;
  c.h = __builtin_amdgcn_cvt_pkrtz(lo, hi);
  return c.u;
}
__device__ __forceinline__ float fdot2f(unsigned a, unsigned b, float c) {
#if __has_builtin(__builtin_amdgcn_fdot2)
  return __builtin_amdgcn_fdot2(bc_h2(a), bc_h2(b), c, false);
#else
  const half2v ha = bc_h2(a), hb = bc_h2(b);
  return c + (float)ha[0] * (float)hb[0] + (float)ha[1] * (float)hb[1];
#endif
}

// Persistent scan on ONE XCD: 256 blocks launched; a leader picks its XCD;
// the 32 blocks there register (slots 0..31) and run; others exit (after a
// 250us fallback window that makes the scheme deadlock-proof even if
// XCC_ID reads garbage). Participant p owns units p*64..p*64+63; wave v owns
// units p*64+4v..+3 (12 weight rows, packed fp16, 240 VGPRs, asm-pinned).
// Exchange: 1024 u64 slots {step-tag, fp16x2}; thread tid polls slot tid.
// All exchange lines live in the chosen XCD's L2 -> visibility ~L2 latency
// instead of the ~2us cross-XCD coherence cycle measured in rounds 7-9.
//
// ROUND 11 FIX: __launch_bounds__(1024, 4). Round 10 omitted the min-waves
// arg -> compiler allocated 64 VGPRs -> all 240 weight regs spilled to
// scratch (VGPR_Count=64, FETCH 84GB, 343ms). 1024-thread block = 4
// waves/SIMD minimum, so min_waves=4 caps nothing extra and raises the
// VGPR budget to 2048/4 = 512/lane.
__global__ __launch_bounds__(NTHR, 4) void gru_scan_kernel(
    const float* __restrict__ ys, const float* __restrict__ wi,
    const float* __restrict__ wh, const float* __restrict__ b,
    const float* __restrict__ bn, __hip_bfloat16* __restrict__ hidden,
    u64* h_pair, unsigned* ctrl) {
  const int tid = threadIdx.x;
  const int wave = tid >> 6;
  const int lane = tid & 63;

  // x_lds oversized to >80KB total LDS => hardware cannot co-schedule two
  // blocks on one CU (belt-and-braces with the ~310 VGPR footprint).
  __shared__ __align__(16) unsigned hq_lds[2][HID / 2];  // 8KB
  __shared__ __align__(16) float x_lds[2][10240];        // 80KB (use [0..511])
  __shared__ unsigned pair_lds[2][32];
  __shared__ int s_p;

  // ---- registration: pick 32 blocks on one XCD (deadlock-proof) ----
  if (tid == 0) {
    unsigned xcc = 0;
    asm volatile("s_getreg_b32 %0, hwreg(20, 0, 32)" : "=s"(xcc));
    xcc &= 0xFu;
    if (atomicCAS(&ctrl[0], 0u, 1u) == 0u)
      __hip_atomic_store(&ctrl[1], 0x80000000u | xcc, __ATOMIC_RELAXED,
                         __HIP_MEMORY_SCOPE_AGENT);
    unsigned ch;
    do {
      ch = __hip_atomic_load(&ctrl[1], __ATOMIC_RELAXED,
                             __HIP_MEMORY_SCOPE_AGENT);
      if (!(ch >> 31)) __builtin_amdgcn_s_sleep(8);
    } while (!(ch >> 31));
    if ((ch & 0xFu) != xcc) {
      // fallback: wait 250us (100MHz realtime clock), then register anyway
      const u64 t0 = __builtin_amdgcn_s_memrealtime();
      while (__builtin_amdgcn_s_memrealtime() - t0 < 25000ull) {
        if (__hip_atomic_load(&ctrl[2], __ATOMIC_RELAXED,
                              __HIP_MEMORY_SCOPE_AGENT) >= NPART)
          break;
        __builtin_amdgcn_s_sleep(32);
      }
    }
    const unsigned slot = atomicAdd(&ctrl[2], 1u);
    s_p = (slot < NPART) ? (int)slot : -1;
  }
  __syncthreads();
  const int p = s_p;
  if (p < 0) return;

  // ---- one-time: stage 12 rows/wave of wh,wi as packed fp16 in VGPRs ----
  // Wave owns units base+4v+e (e=0..3); rows {u, H+u, 2H+u}; idx = e*3+g.
  const int base = p * 64;
  unsigned whp[12][16];
  unsigned wip[12][4];
#pragma unroll
  for (int e = 0; e < 4; ++e) {
#pragma unroll
    for (int g = 0; g < 3; ++g) {
      const int idx = e * 3 + g;
      const size_t R = (size_t)(g * HID + base + wave * 4 + e);
#pragma unroll
      for (int m = 0; m < 8; ++m) {
        const float4 q =
            *reinterpret_cast<const float4*>(wh + R * HID + m * 256 + lane * 4);
        whp[idx][2 * m] = pk_rn(q.x, q.y);
        whp[idx][2 * m + 1] = pk_rn(q.z, q.w);
      }
#pragma unroll
      for (int pp = 0; pp < 2; ++pp) {
        const float4 q =
            *reinterpret_cast<const float4*>(wi + R * 512 + pp * 256 + lane * 4);
        wip[idx][2 * pp] = pk_rn(q.x, q.y);
        wip[idx][2 * pp + 1] = pk_rn(q.z, q.w);
      }
    }
  }
#pragma unroll
  for (int r = 0; r < 12; ++r) {
#pragma unroll
    for (int m = 0; m < 16; ++m) asm volatile("" : "+v"(whp[r][m]));
#pragma unroll
    for (int q = 0; q < 4; ++q) asm volatile("" : "+v"(wip[r][q]));
  }

  // Gate constants for unit e = lane&3 of this wave.
  const int iu = base + wave * 4 + (lane & 3);
  const float b_r = b[iu];
  const float b_z = b[HID + iu];
  const float b_n = b[2 * HID + iu];
  const float bn_v = bn[iu];

  float h_own = 0.f;

#pragma unroll 1
  for (int s = 0; s < T_STEPS; ++s) {
    const int buf = s & 1;
    const u64* hp = h_pair + buf * (HID / 2);
    u64* hp_next = h_pair + (buf ^ 1) * (HID / 2);
    const unsigned tag = (unsigned)s;

    float y = 0.f;
    if (tid < 512) y = ys[(size_t)s * OBS + (tid & 255)];

    // ---- poll own slot: ONE u64 per thread ----
    u64 v = __hip_atomic_load(hp + tid, __ATOMIC_RELAXED,
                              __HIP_MEMORY_SCOPE_AGENT);
    while ((unsigned)(v >> 32) != tag) {
      __builtin_amdgcn_s_sleep(1);
      v = __hip_atomic_load(hp + tid, __ATOMIC_RELAXED,
                            __HIP_MEMORY_SCOPE_AGENT);
    }
    hq_lds[buf][tid] = (unsigned)v;
    if (tid < 512) {
      const bool good = (y == y);  // !isnan
      x_lds[buf][tid] = (tid < 256) ? (good ? y : 0.f) : (good ? 1.f : 0.f);
    }
    __syncthreads();  // sync1

    // ---- fragments ----
    unsigned hq[16], xq[4];
#pragma unroll
    for (int m = 0; m < 8; ++m) {
      const uint2 q =
          *reinterpret_cast<const uint2*>(&hq_lds[buf][m * 128 + lane * 2]);
      hq[2 * m] = q.x;
      hq[2 * m + 1] = q.y;
    }
#pragma unroll
    for (int pp = 0; pp < 2; ++pp) {
      const float4 q =
          *reinterpret_cast<const float4*>(&x_lds[buf][pp * 256 + lane * 4]);
      xq[2 * pp] = pk_rtz(q.x, q.y);
      xq[2 * pp + 1] = pk_rtz(q.z, q.w);
    }

    // ---- 16 accumulators: a[4e+{0:r,1:z,2:hn,3:in}] for units e=0..3 ----
    float a[16];
#pragma unroll
    for (int e = 0; e < 4; ++e) {
      float ar = 0.f, az = 0.f, ahn = 0.f, ain = 0.f;
      const int r0 = e * 3, r1 = e * 3 + 1, r2 = e * 3 + 2;
#pragma unroll
      for (int m = 0; m < 16; ++m) {
        ar = fdot2f(whp[r0][m], hq[m], ar);
        az = fdot2f(whp[r1][m], hq[m], az);
        ahn = fdot2f(whp[r2][m], hq[m], ahn);
      }
#pragma unroll
      for (int q = 0; q < 4; ++q) {
        ar = fdot2f(wip[r0][q], xq[q], ar);
        az = fdot2f(wip[r1][q], xq[q], az);
        ain = fdot2f(wip[r2][q], xq[q], ain);
      }
      a[4 * e] = ar;
      a[4 * e + 1] = az;
      a[4 * e + 2] = ahn;
      a[4 * e + 3] = ain;
    }

    // ---- combining butterfly: 16 sums in 15+2 shuffles ----
    // comp c=(c3c2c1c0) ends at lane&15 = c3 | c2<<1 | c1<<2 | c0<<3.
#pragma unroll
    for (int j = 0; j < 8; ++j) {
      const bool sel = (lane & 1) != 0;
      const float keep = sel ? a[j + 8] : a[j];
      const float send = sel ? a[j] : a[j + 8];
      a[j] = keep + __shfl_xor(send, 1, 64);
    }
#pragma unroll
    for (int j = 0; j < 4; ++j) {
      const bool sel = (lane & 2) != 0;
      const float keep = sel ? a[j + 4] : a[j];
      const float send = sel ? a[j] : a[j + 4];
      a[j] = keep + __shfl_xor(send, 2, 64);
    }
#pragma unroll
    for (int j = 0; j < 2; ++j) {
      const bool sel = (lane & 4) != 0;
      const float keep = sel ? a[j + 2] : a[j];
      const float send = sel ? a[j] : a[j + 2];
      a[j] = keep + __shfl_xor(send, 4, 64);
    }
    {
      const bool sel = (lane & 8) != 0;
      const float keep = sel ? a[1] : a[0];
      const float send = sel ? a[0] : a[1];
      a[0] = keep + __shfl_xor(send, 8, 64);
    }
    float redv = a[0];
    redv += __shfl_xor(redv, 16, 64);
    redv += __shfl_xor(redv, 32, 64);

    // gather: comp c=4e+part at lane (e>>1) + 2*(e&1) + 4*(part>>1) + 8*(part&1)
    const int e = lane & 3;
    const int bsrc = ((e & 1) << 1) | (e >> 1);
    const float d_r = __shfl(redv, bsrc, 64);
    const float d_z = __shfl(redv, bsrc + 8, 64);
    const float d_hn = __shfl(redv, bsrc + 4, 64);
    const float d_in = __shfl(redv, bsrc + 12, 64);

    // ---- gate math (valid everywhere; lanes 0..3 hold the real state) ----
    const float rg = 1.f / (1.f + expf(-(d_r + b_r)));
    const float zg = 1.f / (1.f + expf(-(d_z + b_z)));
    const float ng = tanhf(d_in + b_n + rg * (d_hn + bn_v));
    const float hnew = ng + zg * (h_own - ng);
    h_own = hnew;

    const float h_nb = __shfl_xor(hnew, 1, 64);  // partner unit's h
    if (lane < 4 && !(lane & 1)) {  // lanes 0,2: pairs (e0,e1),(e2,e3)
      pair_lds[buf][wave * 2 + (lane >> 1)] = pk_rtz(hnew, h_nb);
      const unsigned bfp =
          ((unsigned)__bfloat16_as_ushort(__float2bfloat16(h_nb)) << 16) |
          (unsigned)__bfloat16_as_ushort(__float2bfloat16(hnew));
      *reinterpret_cast<unsigned*>(
          &hidden[(size_t)s * HID + base + wave * 4 + lane]) = bfp;
    }
    __syncthreads();  // sync2

    // ---- publish: 32 tagged u64 (one 256B burst) ----
    if (tid < 32) {
      const u64 pv = ((u64)(tag + 1) << 32) | (u64)pair_lds[buf][tid];
      __hip_atomic_store(hp_next + p * 32 + tid, pv, __ATOMIC_RELAXED,
                         __HIP_MEMORY_SCOPE_AGENT);
    }
  }
}

// out[t][o] = bl[o] + sum_k hidden[t][k] * Wl[o][k]
__global__ __launch_bounds__(256) void out_gemm_kernel(
    const __hip_bfloat16* __restrict__ hidden, const float* __restrict__ Wl,
    const float* __restrict__ bl, float* __restrict__ out) {
  __shared__ float As[16][68];
  __shared__ float Bs[16][68];
  const int tid = threadIdx.x;
  const int bt = blockIdx.x * 64;
  const int bo = blockIdx.y * 64;
  const int tx = tid & 15;
  const int ty = tid >> 4;
  const int tA = tid >> 2;
  const int kq = (tid & 3) << 2;
  const unsigned short* hidu = reinterpret_cast<const unsigned short*>(hidden);

  float acc[4][4];
#pragma unroll
  for (int i = 0; i < 4; ++i)
#pragma unroll
    for (int j = 0; j < 4; ++j) acc[i][j] = 0.f;

  for (int k0 = 0; k0 < HID; k0 += 16) {
    const ushort4 av = *reinterpret_cast<const ushort4*>(
        hidu + (size_t)(bt + tA) * HID + k0 + kq);
    As[kq + 0][tA] = __uint_as_float((unsigned)av.x << 16);
    As[kq + 1][tA] = __uint_as_float((unsigned)av.y << 16);
    As[kq + 2][tA] = __uint_as_float((unsigned)av.z << 16);
    As[kq + 3][tA] = __uint_as_float((unsigned)av.w << 16);
    const float4 bv = *reinterpret_cast<const float4*>(
        Wl + (size_t)(bo + tA) * HID + k0 + kq);
    Bs[kq + 0][tA] = bv.x;
    Bs[kq + 1][tA] = bv.y;
    Bs[kq + 2][tA] = bv.z;
    Bs[kq + 3][tA] = bv.w;
    __syncthreads();
#pragma unroll
    for (int k = 0; k < 16; ++k) {
      const float4 a = *reinterpret_cast<const float4*>(&As[k][ty << 2]);
      const float4 bq = *reinterpret_cast<const float4*>(&Bs[k][tx << 2]);
      const float a4[4] = {a.x, a.y, a.z, a.w};
      const float b4[4] = {bq.x, bq.y, bq.z, bq.w};
#pragma unroll
      for (int i = 0; i < 4; ++i)
#pragma unroll
        for (int j = 0; j < 4; ++j) acc[i][j] += a4[i] * b4[j];
    }
    __syncthreads();
  }
#pragma unroll
  for (int i = 0; i < 4; ++i) {
    const int t = bt + (ty << 2) + i;
#pragma unroll
    for (int j = 0; j < 4; ++j) {
      const int o = bo + (tx << 2) + j;
      out[(size_t)t * NOUT + o] = acc[i][j] + bl[o];
    }
  }
}

extern "C" void kernel_launch(void* const* d_in, const int* in_sizes, int n_in,
                              void* d_out, int out_size, void* d_ws,
                              size_t ws_size, hipStream_t stream) {
  (void)in_sizes;
  (void)n_in;
  (void)out_size;
  (void)ws_size;
  // setup_inputs order: ts, ys, wi, wh, b, bn, Wl, bl (all f32)
  const float* ys = (const float*)d_in[1];
  const float* wi = (const float*)d_in[2];
  const float* wh = (const float*)d_in[3];
  const float* b = (const float*)d_in[4];
  const float* bn = (const float*)d_in[5];
  const float* Wl = (const float*)d_in[6];
  const float* bl = (const float*)d_in[7];
  float* out = (float*)d_out;

  unsigned* ctrl = (unsigned*)((char*)d_ws + WS_CTRL_OFF);
  u64* h_pair = (u64*)((char*)d_ws + WS_HBUF_OFF);
  __hip_bfloat16* hidden = (__hip_bfloat16*)((char*)d_ws + WS_HIDDEN_OFF);

  gru_init_kernel<<<8, 256, 0, stream>>>(h_pair, ctrl);

  gru_scan_kernel<<<dim3(256), dim3(NTHR), 0, stream>>>(ys, wi, wh, b, bn,
                                                        hidden, h_pair, ctrl);

  out_gemm_kernel<<<dim3(T_STEPS / 64, NOUT / 64), 256, 0, stream>>>(
      hidden, Wl, bl, out);
}

// Round 12
// 45789.703 us; speedup vs baseline: 7.5047x; 7.5000x over previous
//
#include <hip/hip_runtime.h>
#include <hip/hip_bf16.h>

#define T_STEPS 8192
#define OBS 256
#define HID 2048
#define NOUT 256

#define NBLK 64   // scan blocks, 1/CU, 4 waves each => 256 free-running waves
#define NTHR 256

typedef unsigned long long u64;
typedef _Float16 half2v __attribute__((ext_vector_type(2)));
typedef __fp16 fp16x2 __attribute__((ext_vector_type(2)));

// ws layout:
//   [4096, 20480)  : h_pair, 2 buffers x 1024 u64 {tag:u32 (hi), fp16x2 (lo)}
//   [65536, +32MB) : hidden, T x HID bf16
#define WS_HBUF_OFF 4096
#define WS_HIDDEN_OFF 65536

__global__ void gru_init_kernel(u64* h_pair) {
  h_pair[blockIdx.x * 256 + threadIdx.x] = 0ull;  // 2048 u64
}

__device__ __forceinline__ half2v bc_h2(unsigned u) {
  union { unsigned u; half2v h; } c;
  c.u = u;
  return c.h;
}
__device__ __forceinline__ unsigned pk_rn(float lo, float hi) {
  union { half2v h; unsigned u; } c;
  c.h[0] = (_Float16)lo;  // RNE
  c.h[1] = (_Float16)hi;
  return c.u;
}
__device__ __forceinline__ unsigned pk_rtz(float lo, float hi) {
  union { fp16x2 h; unsigned u; } c;
  c.h = __builtin_amdgcn_cvt_pkrtz(lo, hi);
  return c.u;
}
__device__ __forceinline__ float fdot2f(unsigned a, unsigned b, float c) {
#if __has_builtin(__builtin_amdgcn_fdot2)
  return __builtin_amdgcn_fdot2(bc_h2(a), bc_h2(b), c, false);
#else
  const half2v ha = bc_h2(a), hb = bc_h2(b);
  return c + (float)ha[0] * (float)hb[0] + (float)ha[1] * (float)hb[1];
#endif
}

// Accumulate one arrived h-pair group m into all 24 wh-dots (static indices).
#define ACC_GROUP(m)                                        \
  {                                                         \
    const unsigned h0 = (unsigned)va[m];                    \
    const unsigned h1 = (unsigned)vb[m];                    \
    _Pragma("unroll") for (int e = 0; e < 8; ++e) {         \
      aR[e] = fdot2f(whp[e][0][2 * (m)], h0, aR[e]);        \
      aR[e] = fdot2f(whp[e][0][2 * (m) + 1], h1, aR[e]);    \
      aZ[e] = fdot2f(whp[e][1][2 * (m)], h0, aZ[e]);        \
      aZ[e] = fdot2f(whp[e][1][2 * (m) + 1], h1, aZ[e]);    \
      aHN[e] = fdot2f(whp[e][2][2 * (m)], h0, aHN[e]);      \
      aHN[e] = fdot2f(whp[e][2][2 * (m) + 1], h1, aHN[e]);  \
    }                                                       \
  }

// 64 blocks x 256 threads (1 wave/SIMD => 512 VGPR budget). Global wave gwid
// owns units gwid*8..+7: wh rows {u,H+u,2H+u} packed fp16 in 384 VGPRs
// (asm-pinned). wi left half (ys part) lives in LDS (48KB, fp16); wi right
// half (NaN-mask part) is folded into a per-unit constant c_g = b + rowsum
// (mask==1 when no NaNs; exact rare slow path subtracts wi_right·indicator).
// NO barriers in the step loop: each wave polls exactly the 16 slot-u64s its
// dot consumes, accumulates groups incrementally as they arrive, and
// publishes its own 4 adjacent slots. Tag protocol (r6-r9) unchanged.
__global__ __launch_bounds__(NTHR, 1) void gru_scan_kernel(
    const float* __restrict__ ys, const float* __restrict__ wi,
    const float* __restrict__ wh, const float* __restrict__ b,
    const float* __restrict__ bn, __hip_bfloat16* __restrict__ hidden,
    u64* h_pair) {
  const int tid = threadIdx.x;
  const int wave = tid >> 6;
  const int lane = tid & 63;
  const int gwid = blockIdx.x * 4 + wave;  // 0..255
  const int ubase = gwid * 8;

  __shared__ unsigned wi_lds[96][128];  // [local_unit*3+g][lane*2+k], 48KB

  // ---- one-time: wh -> 384 packed fp16 VGPRs; wi_left -> LDS ----
  unsigned whp[8][3][16];
#pragma unroll
  for (int e = 0; e < 8; ++e)
#pragma unroll
    for (int g = 0; g < 3; ++g) {
      const size_t R = (size_t)(g * HID + ubase + e);
#pragma unroll
      for (int m = 0; m < 8; ++m) {
        const float4 q =
            *reinterpret_cast<const float4*>(wh + R * HID + m * 256 + lane * 4);
        whp[e][g][2 * m] = pk_rn(q.x, q.y);
        whp[e][g][2 * m + 1] = pk_rn(q.z, q.w);
      }
      const float4 q =
          *reinterpret_cast<const float4*>(wi + R * 512 + lane * 4);
      wi_lds[(wave * 8 + e) * 3 + g][lane * 2] = pk_rn(q.x, q.y);
      wi_lds[(wave * 8 + e) * 3 + g][lane * 2 + 1] = pk_rn(q.z, q.w);
    }
#pragma unroll
  for (int e = 0; e < 8; ++e)
#pragma unroll
    for (int g = 0; g < 3; ++g)
#pragma unroll
      for (int m = 0; m < 16; ++m) asm volatile("" : "+v"(whp[e][g][m]));

  // ---- constants: c_g(unit) = b + rowsum(wi_right); bn ----
  float cg[3];
  {
    const int em = lane & 7;
#pragma unroll
    for (int g = 0; g < 3; ++g) cg[g] = b[g * HID + ubase + em];
#pragma unroll
    for (int e = 0; e < 8; ++e)
#pragma unroll
      for (int g = 0; g < 3; ++g) {
        const size_t R = (size_t)(g * HID + ubase + e);
        const float4 q =
            *reinterpret_cast<const float4*>(wi + R * 512 + 256 + lane * 4);
        float r = q.x + q.y + q.z + q.w;
#pragma unroll
        for (int off = 32; off; off >>= 1) r += __shfl_xor(r, off, 64);
        if (em == e) cg[g] += r;
      }
  }
  const float bn_v = bn[ubase + (lane & 7)];
  __syncthreads();  // wi_lds ready (the ONLY barrier; none in the loop)

  float h_own = 0.f;
  // gather base: unit e=lane&7 -> comp lane E=(e0<<4)|(e1<<3)|(e2<<2)
  const int E = ((lane & 1) << 4) | ((lane & 2) << 2) | (lane & 4);

#pragma unroll 1
  for (int s = 0; s < T_STEPS; ++s) {
    const u64* hp = h_pair + (s & 1) * 1024;
    u64* hpn = h_pair + ((s + 1) & 1) * 1024;
    const unsigned tag = (unsigned)s;

    // independent ys load first (latency hidden under slot processing)
    const float4 yv =
        *reinterpret_cast<const float4*>(ys + (size_t)s * OBS + lane * 4);

    // issue ALL 16 slot loads back-to-back (groups m: pairs m*128+2l, +1)
    u64 va[8], vb[8];
#pragma unroll
    for (int m = 0; m < 8; ++m) {
      va[m] = __hip_atomic_load(hp + m * 128 + 2 * lane, __ATOMIC_RELAXED,
                                __HIP_MEMORY_SCOPE_AGENT);
      vb[m] = __hip_atomic_load(hp + m * 128 + 2 * lane + 1, __ATOMIC_RELAXED,
                                __HIP_MEMORY_SCOPE_AGENT);
    }

    float aR[8], aZ[8], aHN[8], aIN[8];
#pragma unroll
    for (int e = 0; e < 8; ++e) {
      aR[e] = 0.f;
      aZ[e] = 0.f;
      aHN[e] = 0.f;
      aIN[e] = 0.f;
    }

    // x pack + NaN handling (wave covers all 256 obs: 4/lane)
    const bool k0 = (yv.x == yv.x), k1 = (yv.y == yv.y), k2 = (yv.z == yv.z),
               k3 = (yv.w == yv.w);
    const unsigned xq0 = pk_rtz(k0 ? yv.x : 0.f, k1 ? yv.y : 0.f);
    const unsigned xq1 = pk_rtz(k2 ? yv.z : 0.f, k3 ? yv.w : 0.f);
    const bool anybad = __any(!(k0 && k1 && k2 && k3));

    // wi_left dots from LDS
#pragma unroll
    for (int e = 0; e < 8; ++e) {
      const int rb = (wave * 8 + e) * 3;
      const uint2 w0 = *reinterpret_cast<const uint2*>(&wi_lds[rb][lane * 2]);
      const uint2 w1 =
          *reinterpret_cast<const uint2*>(&wi_lds[rb + 1][lane * 2]);
      const uint2 w2 =
          *reinterpret_cast<const uint2*>(&wi_lds[rb + 2][lane * 2]);
      aR[e] = fdot2f(w0.x, xq0, aR[e]);
      aR[e] = fdot2f(w0.y, xq1, aR[e]);
      aZ[e] = fdot2f(w1.x, xq0, aZ[e]);
      aZ[e] = fdot2f(w1.y, xq1, aZ[e]);
      aIN[e] = fdot2f(w2.x, xq0, aIN[e]);
      aIN[e] = fdot2f(w2.y, xq1, aIN[e]);
    }

    if (anybad) {  // rare exact path: subtract wi_right·indicator
      const unsigned n0 = pk_rtz(k0 ? 0.f : -1.f, k1 ? 0.f : -1.f);
      const unsigned n1 = pk_rtz(k2 ? 0.f : -1.f, k3 ? 0.f : -1.f);
#pragma unroll
      for (int e = 0; e < 8; ++e)
#pragma unroll
        for (int g = 0; g < 3; ++g) {
          const size_t R = (size_t)(g * HID + ubase + e);
          const float4 q =
              *reinterpret_cast<const float4*>(wi + R * 512 + 256 + lane * 4);
          float t = 0.f;
          t = fdot2f(pk_rtz(q.x, q.y), n0, t);
          t = fdot2f(pk_rtz(q.z, q.w), n1, t);
          if (g == 0)
            aR[e] += t;
          else if (g == 1)
            aZ[e] += t;
          else
            aIN[e] += t;
        }
    }

    // ---- incremental arrival: accumulate each group as its tags land ----
    unsigned pend = 0xFFu;
#pragma unroll
    for (int m = 0; m < 8; ++m) {
      if ((unsigned)(va[m] >> 32) == tag && (unsigned)(vb[m] >> 32) == tag) {
        pend &= ~(1u << m);
        ACC_GROUP(m);
      }
    }
    while (pend) {
      __builtin_amdgcn_s_sleep(1);
#pragma unroll
      for (int m = 0; m < 8; ++m) {
        if (pend & (1u << m)) {
          va[m] = __hip_atomic_load(hp + m * 128 + 2 * lane, __ATOMIC_RELAXED,
                                    __HIP_MEMORY_SCOPE_AGENT);
          vb[m] =
              __hip_atomic_load(hp + m * 128 + 2 * lane + 1, __ATOMIC_RELAXED,
                                __HIP_MEMORY_SCOPE_AGENT);
          if ((unsigned)(va[m] >> 32) == tag &&
              (unsigned)(vb[m] >> 32) == tag) {
            pend &= ~(1u << m);
            ACC_GROUP(m);
          }
        }
      }
    }

    // ---- combining butterfly: 32 sums in 32 shuffles ----
    float a[32];
#pragma unroll
    for (int e = 0; e < 8; ++e) {
      a[e] = aR[e];
      a[8 + e] = aZ[e];
      a[16 + e] = aHN[e];
      a[24 + e] = aIN[e];
    }
#pragma unroll
    for (int j = 0; j < 16; ++j) {
      const bool sel = (lane & 1) != 0;
      const float keep = sel ? a[j + 16] : a[j];
      const float send = sel ? a[j] : a[j + 16];
      a[j] = keep + __shfl_xor(send, 1, 64);
    }
#pragma unroll
    for (int j = 0; j < 8; ++j) {
      const bool sel = (lane & 2) != 0;
      const float keep = sel ? a[j + 8] : a[j];
      const float send = sel ? a[j] : a[j + 8];
      a[j] = keep + __shfl_xor(send, 2, 64);
    }
#pragma unroll
    for (int j = 0; j < 4; ++j) {
      const bool sel = (lane & 4) != 0;
      const float keep = sel ? a[j + 4] : a[j];
      const float send = sel ? a[j] : a[j + 4];
      a[j] = keep + __shfl_xor(send, 4, 64);
    }
#pragma unroll
    for (int j = 0; j < 2; ++j) {
      const bool sel = (lane & 8) != 0;
      const float keep = sel ? a[j + 2] : a[j];
      const float send = sel ? a[j] : a[j + 2];
      a[j] = keep + __shfl_xor(send, 8, 64);
    }
    {
      const bool sel = (lane & 16) != 0;
      const float keep = sel ? a[1] : a[0];
      const float send = sel ? a[0] : a[1];
      a[0] = keep + __shfl_xor(send, 16, 64);
    }
    const float redv = a[0] + __shfl_xor(a[0], 32, 64);

    // comp c=q*8+e at lane {bit0=q1,bit1=q0,bit2=e2,bit3=e1,bit4=e0}
    const float d_r = __shfl(redv, E, 64);
    const float d_z = __shfl(redv, E + 2, 64);
    const float d_hn = __shfl(redv, E + 1, 64);
    const float d_in = __shfl(redv, E + 3, 64);

    // ---- gate math on all lanes (unit e = lane&7) ----
    const float rg = 1.f / (1.f + expf(-(d_r + cg[0])));
    const float zg = 1.f / (1.f + expf(-(d_z + cg[1])));
    const float ng = tanhf(d_in + cg[2] + rg * (d_hn + bn_v));
    const float hnew = ng + zg * (h_own - ng);
    h_own = hnew;

    // ---- per-wave publish: 4 adjacent tagged u64 (32B burst) ----
    const float h1v = __shfl_xor(hnew, 1, 64);
    if (lane < 8 && !(lane & 1)) {
      const u64 pv = ((u64)(tag + 1) << 32) | (u64)pk_rtz(hnew, h1v);
      __hip_atomic_store(hpn + gwid * 4 + (lane >> 1), pv, __ATOMIC_RELAXED,
                         __HIP_MEMORY_SCOPE_AGENT);
      const unsigned bfp =
          ((unsigned)__bfloat16_as_ushort(__float2bfloat16(h1v)) << 16) |
          (unsigned)__bfloat16_as_ushort(__float2bfloat16(hnew));
      *reinterpret_cast<unsigned*>(
          &hidden[(size_t)s * HID + ubase + lane]) = bfp;
    }
  }
}

// out[t][o] = bl[o] + sum_k hidden[t][k] * Wl[o][k]
__global__ __launch_bounds__(256) void out_gemm_kernel(
    const __hip_bfloat16* __restrict__ hidden, const float* __restrict__ Wl,
    const float* __restrict__ bl, float* __restrict__ out) {
  __shared__ float As[16][68];
  __shared__ float Bs[16][68];
  const int tid = threadIdx.x;
  const int bt = blockIdx.x * 64;
  const int bo = blockIdx.y * 64;
  const int tx = tid & 15;
  const int ty = tid >> 4;
  const int tA = tid >> 2;
  const int kq = (tid & 3) << 2;
  const unsigned short* hidu = reinterpret_cast<const unsigned short*>(hidden);

  float acc[4][4];
#pragma unroll
  for (int i = 0; i < 4; ++i)
#pragma unroll
    for (int j = 0; j < 4; ++j) acc[i][j] = 0.f;

  for (int k0 = 0; k0 < HID; k0 += 16) {
    const ushort4 av = *reinterpret_cast<const ushort4*>(
        hidu + (size_t)(bt + tA) * HID + k0 + kq);
    As[kq + 0][tA] = __uint_as_float((unsigned)av.x << 16);
    As[kq + 1][tA] = __uint_as_float((unsigned)av.y << 16);
    As[kq + 2][tA] = __uint_as_float((unsigned)av.z << 16);
    As[kq + 3][tA] = __uint_as_float((unsigned)av.w << 16);
    const float4 bv = *reinterpret_cast<const float4*>(
        Wl + (size_t)(bo + tA) * HID + k0 + kq);
    Bs[kq + 0][tA] = bv.x;
    Bs[kq + 1][tA] = bv.y;
    Bs[kq + 2][tA] = bv.z;
    Bs[kq + 3][tA] = bv.w;
    __syncthreads();
#pragma unroll
    for (int k = 0; k < 16; ++k) {
      const float4 a = *reinterpret_cast<const float4*>(&As[k][ty << 2]);
      const float4 bq = *reinterpret_cast<const float4*>(&Bs[k][tx << 2]);
      const float a4[4] = {a.x, a.y, a.z, a.w};
      const float b4[4] = {bq.x, bq.y, bq.z, bq.w};
#pragma unroll
      for (int i = 0; i < 4; ++i)
#pragma unroll
        for (int j = 0; j < 4; ++j) acc[i][j] += a4[i] * b4[j];
    }
    __syncthreads();
  }
#pragma unroll
  for (int i = 0; i < 4; ++i) {
    const int t = bt + (ty << 2) + i;
#pragma unroll
    for (int j = 0; j < 4; ++j) {
      const int o = bo + (tx << 2) + j;
      out[(size_t)t * NOUT + o] = acc[i][j] + bl[o];
    }
  }
}

extern "C" void kernel_launch(void* const* d_in, const int* in_sizes, int n_in,
                              void* d_out, int out_size, void* d_ws,
                              size_t ws_size, hipStream_t stream) {
  (void)in_sizes;
  (void)n_in;
  (void)out_size;
  (void)ws_size;
  // setup_inputs order: ts, ys, wi, wh, b, bn, Wl, bl (all f32)
  const float* ys = (const float*)d_in[1];
  const float* wi = (const float*)d_in[2];
  const float* wh = (const float*)d_in[3];
  const float* b = (const float*)d_in[4];
  const float* bn = (const float*)d_in[5];
  const float* Wl = (const float*)d_in[6];
  const float* bl = (const float*)d_in[7];
  float* out = (float*)d_out;

  u64* h_pair = (u64*)((char*)d_ws + WS_HBUF_OFF);
  __hip_bfloat16* hidden = (__hip_bfloat16*)((char*)d_ws + WS_HIDDEN_OFF);

  gru_init_kernel<<<8, 256, 0, stream>>>(h_pair);

  gru_scan_kernel<<<dim3(NBLK), dim3(NTHR), 0, stream>>>(ys, wi, wh, b, bn,
                                                         hidden, h_pair);

  out_gemm_kernel<<<dim3(T_STEPS / 64, NOUT / 64), 256, 0, stream>>>(
      hidden, Wl, bl, out);
}

// Round 13
// 30750.601 us; speedup vs baseline: 11.1751x; 1.4891x over previous
//
#include <hip/hip_runtime.h>
#include <hip/hip_bf16.h>

#define T_STEPS 8192
#define OBS 256
#define HID 2048
#define NOUT 256

#define NBLK 128  // scan blocks (1/CU)
#define NTHR 512  // 8 waves; wave owns 2 units (6 weight rows, ~120 regs)

typedef unsigned long long u64;
typedef _Float16 half2v __attribute__((ext_vector_type(2)));
typedef __fp16 fp16x2 __attribute__((ext_vector_type(2)));

// ws layout:
//   [4096, 20480)  : h_pair, 2 buffers x 1024 u64 {tag:u32 (hi), fp16x2 (lo)}
//                    slot j of a buffer = hidden units 2j, 2j+1
//   [65536, +32MB) : hidden, T x HID bf16
#define WS_HBUF_OFF 4096
#define WS_HIDDEN_OFF 65536

__global__ void gru_init_kernel(u64* h_pair) {
  h_pair[blockIdx.x * 256 + threadIdx.x] = 0ull;  // 2048 u64
}

__device__ __forceinline__ half2v bc_h2(unsigned u) {
  union { unsigned u; half2v h; } c;
  c.u = u;
  return c.h;
}
__device__ __forceinline__ unsigned pk_rn(float lo, float hi) {
  union { half2v h; unsigned u; } c;
  c.h[0] = (_Float16)lo;  // RNE
  c.h[1] = (_Float16)hi;
  return c.u;
}
__device__ __forceinline__ unsigned pk_rtz(float lo, float hi) {
  union { fp16x2 h; unsigned u; } c;
  c.h = __builtin_amdgcn_cvt_pkrtz(lo, hi);
  return c.u;
}
__device__ __forceinline__ float fdot2f(unsigned a, unsigned b, float c) {
#if __has_builtin(__builtin_amdgcn_fdot2)
  return __builtin_amdgcn_fdot2(bc_h2(a), bc_h2(b), c, false);
#else
  const half2v ha = bc_h2(a), hb = bc_h2(b);
  return c + (float)ha[0] * (float)hb[0] + (float)ha[1] * (float)hb[1];
#endif
}

// r13 = r9 structure minus the aggregation barrier (sync2):
// 128 blocks x 512 threads. Block w owns units w*16..+15; wave v owns units
// w*16+2v, +2v+1 (weight rows {i,H+i,2H+i} packed fp16 in VGPRs, asm-pinned).
// Exchange: 1024 independently-tagged u64 slots; wave v of block w publishes
// slot w*8+v ITSELF (lane 0) right after its gate math — no cross-wave
// aggregation, ONE barrier per step (sync1, staging). Safety: a wave
// publishes s+1 only after block-wide sync1(s), which needs all slots at tag
// s, which implies every block passed sync1(s-1) and has consumed the buffer
// being overwritten (same induction as r9, one barrier less).
__global__ __launch_bounds__(NTHR, 2) void gru_scan_kernel(
    const float* __restrict__ ys, const float* __restrict__ wi,
    const float* __restrict__ wh, const float* __restrict__ b,
    const float* __restrict__ bn, __hip_bfloat16* __restrict__ hidden,
    u64* h_pair) {
  const int w = blockIdx.x;
  const int tid = threadIdx.x;
  const int wave = tid >> 6;
  const int lane = tid & 63;

  __shared__ __align__(16) unsigned hq_lds[2][HID / 2];  // fp16x2 pairs, 2x4KB
  __shared__ __align__(16) float x_lds[2][2 * OBS];      // 2x2KB

  // ---- one-time: stage 6 rows/wave of wh,wi as packed fp16 in VGPRs ----
  unsigned whp[6][16];
  unsigned wip[6][4];
#pragma unroll
  for (int r = 0; r < 6; ++r) {
    const int g = r >> 1, e = r & 1;
    const size_t R = (size_t)(g * HID + w * 16 + 2 * wave + e);
#pragma unroll
    for (int m = 0; m < 8; ++m) {
      const float4 q =
          *reinterpret_cast<const float4*>(wh + R * HID + m * 256 + lane * 4);
      whp[r][2 * m] = pk_rn(q.x, q.y);
      whp[r][2 * m + 1] = pk_rn(q.z, q.w);
    }
#pragma unroll
    for (int p = 0; p < 2; ++p) {
      const float4 q =
          *reinterpret_cast<const float4*>(wi + R * 512 + p * 256 + lane * 4);
      wip[r][2 * p] = pk_rn(q.x, q.y);
      wip[r][2 * p + 1] = pk_rn(q.z, q.w);
    }
  }
#pragma unroll
  for (int r = 0; r < 6; ++r) {
#pragma unroll
    for (int m = 0; m < 16; ++m) asm volatile("" : "+v"(whp[r][m]));
#pragma unroll
    for (int p = 0; p < 4; ++p) asm volatile("" : "+v"(wip[r][p]));
  }

  // Gate constants for this wave's unit (lane&1 selects which of the pair).
  const int iu = w * 16 + 2 * wave + (lane & 1);
  const float b_r = b[iu];
  const float b_z = b[HID + iu];
  const float b_n = b[2 * HID + iu];
  const float bn_v = bn[iu];

  float h_own = 0.f;  // lanes 0,1: f32 recurrence state of own unit

#pragma unroll 1
  for (int s = 0; s < T_STEPS; ++s) {
    const int buf = s & 1;
    const u64* hp = h_pair + buf * 1024;
    u64* hp_next = h_pair + (buf ^ 1) * 1024;
    const unsigned tag = (unsigned)s;

    const float y = ys[(size_t)s * OBS + (tid & 255)];  // overlaps the polls

    // ---- poll 2 adjacent independently-tagged slots; re-load only stale ----
    u64 v0 = __hip_atomic_load(hp + 2 * tid, __ATOMIC_RELAXED,
                               __HIP_MEMORY_SCOPE_AGENT);
    u64 v1 = __hip_atomic_load(hp + 2 * tid + 1, __ATOMIC_RELAXED,
                               __HIP_MEMORY_SCOPE_AGENT);
    while ((unsigned)(v0 >> 32) != tag || (unsigned)(v1 >> 32) != tag) {
      __builtin_amdgcn_s_sleep(1);
      if ((unsigned)(v0 >> 32) != tag)
        v0 = __hip_atomic_load(hp + 2 * tid, __ATOMIC_RELAXED,
                               __HIP_MEMORY_SCOPE_AGENT);
      if ((unsigned)(v1 >> 32) != tag)
        v1 = __hip_atomic_load(hp + 2 * tid + 1, __ATOMIC_RELAXED,
                               __HIP_MEMORY_SCOPE_AGENT);
    }

    // ---- stage packed h pairs and x into this step's LDS buffer ----
    hq_lds[buf][2 * tid] = (unsigned)v0;
    hq_lds[buf][2 * tid + 1] = (unsigned)v1;
    {
      const bool good = (y == y);  // !isnan
      x_lds[buf][tid] = (tid < 256) ? (good ? y : 0.f) : (good ? 1.f : 0.f);
    }
    __syncthreads();  // sync1: the ONLY barrier per step

    // ---- fragments: packed pairs straight from LDS ----
    unsigned hq[16], xq[4];
#pragma unroll
    for (int m = 0; m < 8; ++m) {
      const uint2 q =
          *reinterpret_cast<const uint2*>(&hq_lds[buf][m * 128 + lane * 2]);
      hq[2 * m] = q.x;
      hq[2 * m + 1] = q.y;
    }
#pragma unroll
    for (int p = 0; p < 2; ++p) {
      const float4 q =
          *reinterpret_cast<const float4*>(&x_lds[buf][p * 256 + lane * 4]);
      xq[2 * p] = pk_rtz(q.x, q.y);
      xq[2 * p + 1] = pk_rtz(q.z, q.w);
    }

    // ---- 8 dot accumulators: a[4e+{0:r,1:z,2:wh-n,3:wi-n}] for unit e ----
    float a[8];
#pragma unroll
    for (int e = 0; e < 2; ++e) {
      float ar = 0.f, az = 0.f, ahn = 0.f, ain = 0.f;
      const int r0 = e, r1 = 2 + e, r2 = 4 + e;
#pragma unroll
      for (int m = 0; m < 16; ++m) {
        ar = fdot2f(whp[r0][m], hq[m], ar);
        az = fdot2f(whp[r1][m], hq[m], az);
        ahn = fdot2f(whp[r2][m], hq[m], ahn);
      }
#pragma unroll
      for (int p = 0; p < 4; ++p) {
        ar = fdot2f(wip[r0][p], xq[p], ar);
        az = fdot2f(wip[r1][p], xq[p], az);
        ain = fdot2f(wip[r2][p], xq[p], ain);
      }
      a[4 * e] = ar;
      a[4 * e + 1] = az;
      a[4 * e + 2] = ahn;
      a[4 * e + 3] = ain;
    }

    // ---- combining butterfly: all 8 sums in 10 shuffles ----
#pragma unroll
    for (int j = 0; j < 4; ++j) {
      const bool sel = (lane & 1) != 0;
      const float keep = sel ? a[j + 4] : a[j];
      const float send = sel ? a[j] : a[j + 4];
      a[j] = keep + __shfl_xor(send, 1, 64);
    }
#pragma unroll
    for (int j = 0; j < 2; ++j) {
      const bool sel = (lane & 2) != 0;
      const float keep = sel ? a[j + 2] : a[j];
      const float send = sel ? a[j] : a[j + 2];
      a[j] = keep + __shfl_xor(send, 2, 64);
    }
    {
      const bool sel = (lane & 4) != 0;
      const float keep = sel ? a[1] : a[0];
      const float send = sel ? a[0] : a[1];
      a[0] = keep + __shfl_xor(send, 4, 64);
    }
    float redv = a[0];
    redv += __shfl_xor(redv, 8, 64);
    redv += __shfl_xor(redv, 16, 64);
    redv += __shfl_xor(redv, 32, 64);

    // Component c at lane rev3(c): r_e@lane e, z_e@4+e, hn_e@2+e, in_e@6+e.
    const int e = lane & 1;
    const float d_r = __shfl(redv, e, 64);
    const float d_z = __shfl(redv, 4 + e, 64);
    const float d_hn = __shfl(redv, 2 + e, 64);
    const float d_in = __shfl(redv, 6 + e, 64);

    // ---- gate math on all lanes (only lanes 0,1 hold valid state) ----
    const float rg = 1.f / (1.f + expf(-(d_r + b_r)));
    const float zg = 1.f / (1.f + expf(-(d_z + b_z)));
    const float ng = tanhf(d_in + b_n + rg * (d_hn + bn_v));
    const float hnew = ng + zg * (h_own - ng);
    h_own = hnew;  // garbage on lanes>=2, never consumed

    // ---- per-wave IMMEDIATE publish (lane 0), then off-path bf16 store ----
    const float h1 = __shfl(hnew, 1, 64);
    if (lane == 0) {
      const u64 pv = ((u64)(tag + 1) << 32) | (u64)pk_rtz(hnew, h1);
      __hip_atomic_store(hp_next + (w * 8 + wave), pv, __ATOMIC_RELAXED,
                         __HIP_MEMORY_SCOPE_AGENT);
      const unsigned bf =
          ((unsigned)__bfloat16_as_ushort(__float2bfloat16(h1)) << 16) |
          (unsigned)__bfloat16_as_ushort(__float2bfloat16(hnew));
      *reinterpret_cast<unsigned*>(
          &hidden[(size_t)s * HID + w * 16 + 2 * wave]) = bf;
    }
    // No second barrier: LDS double-buffered by parity; same-parity reuse is
    // separated by two block-wide sync1s (see header comment induction).
  }
}

// out[t][o] = bl[o] + sum_k hidden[t][k] * Wl[o][k]
// 64x64 tile, 256 threads, 4x4 micro-tile, BK=16.
__global__ __launch_bounds__(256) void out_gemm_kernel(
    const __hip_bfloat16* __restrict__ hidden, const float* __restrict__ Wl,
    const float* __restrict__ bl, float* __restrict__ out) {
  __shared__ float As[16][68];
  __shared__ float Bs[16][68];
  const int tid = threadIdx.x;
  const int bt = blockIdx.x * 64;
  const int bo = blockIdx.y * 64;
  const int tx = tid & 15;
  const int ty = tid >> 4;
  const int tA = tid >> 2;
  const int kq = (tid & 3) << 2;
  const unsigned short* hidu = reinterpret_cast<const unsigned short*>(hidden);

  float acc[4][4];
#pragma unroll
  for (int i = 0; i < 4; ++i)
#pragma unroll
    for (int j = 0; j < 4; ++j) acc[i][j] = 0.f;

  for (int k0 = 0; k0 < HID; k0 += 16) {
    const ushort4 av = *reinterpret_cast<const ushort4*>(
        hidu + (size_t)(bt + tA) * HID + k0 + kq);
    As[kq + 0][tA] = __uint_as_float((unsigned)av.x << 16);
    As[kq + 1][tA] = __uint_as_float((unsigned)av.y << 16);
    As[kq + 2][tA] = __uint_as_float((unsigned)av.z << 16);
    As[kq + 3][tA] = __uint_as_float((unsigned)av.w << 16);
    const float4 bv = *reinterpret_cast<const float4*>(
        Wl + (size_t)(bo + tA) * HID + k0 + kq);
    Bs[kq + 0][tA] = bv.x;
    Bs[kq + 1][tA] = bv.y;
    Bs[kq + 2][tA] = bv.z;
    Bs[kq + 3][tA] = bv.w;
    __syncthreads();
#pragma unroll
    for (int k = 0; k < 16; ++k) {
      const float4 a = *reinterpret_cast<const float4*>(&As[k][ty << 2]);
      const float4 bq = *reinterpret_cast<const float4*>(&Bs[k][tx << 2]);
      const float a4[4] = {a.x, a.y, a.z, a.w};
      const float b4[4] = {bq.x, bq.y, bq.z, bq.w};
#pragma unroll
      for (int i = 0; i < 4; ++i)
#pragma unroll
        for (int j = 0; j < 4; ++j) acc[i][j] += a4[i] * b4[j];
    }
    __syncthreads();
  }
#pragma unroll
  for (int i = 0; i < 4; ++i) {
    const int t = bt + (ty << 2) + i;
#pragma unroll
    for (int j = 0; j < 4; ++j) {
      const int o = bo + (tx << 2) + j;
      out[(size_t)t * NOUT + o] = acc[i][j] + bl[o];
    }
  }
}

extern "C" void kernel_launch(void* const* d_in, const int* in_sizes, int n_in,
                              void* d_out, int out_size, void* d_ws,
                              size_t ws_size, hipStream_t stream) {
  (void)in_sizes;
  (void)n_in;
  (void)out_size;
  (void)ws_size;
  // setup_inputs order: ts, ys, wi, wh, b, bn, Wl, bl (all f32)
  const float* ys = (const float*)d_in[1];
  const float* wi = (const float*)d_in[2];
  const float* wh = (const float*)d_in[3];
  const float* b = (const float*)d_in[4];
  const float* bn = (const float*)d_in[5];
  const float* Wl = (const float*)d_in[6];
  const float* bl = (const float*)d_in[7];
  float* out = (float*)d_out;

  u64* h_pair = (u64*)((char*)d_ws + WS_HBUF_OFF);
  __hip_bfloat16* hidden = (__hip_bfloat16*)((char*)d_ws + WS_HIDDEN_OFF);

  gru_init_kernel<<<8, 256, 0, stream>>>(h_pair);

  gru_scan_kernel<<<dim3(NBLK), dim3(NTHR), 0, stream>>>(ys, wi, wh, b, bn,
                                                         hidden, h_pair);

  out_gemm_kernel<<<dim3(T_STEPS / 64, NOUT / 64), 256, 0, stream>>>(
      hidden, Wl, bl, out);
}

// Round 14
// 20873.090 us; speedup vs baseline: 16.4633x; 1.4732x over previous
//
#include <hip/hip_runtime.h>
#include <hip/hip_bf16.h>

#define T_STEPS 8192
#define OBS 256
#define HID 2048
#define NOUT 256

#define NBLK 128   // scan blocks (1/CU on 128 CUs)
#define NTHR 512   // 8 waves; wave owns 2 units
#define NSLOT 512  // 16B seqlock slots (4 units each)

typedef unsigned long long u64;
typedef _Float16 half2v __attribute__((ext_vector_type(2)));
typedef __fp16 fp16x2 __attribute__((ext_vector_type(2)));

// ws layout:
//   [4096, 20480)  : h_pair, 2 buffers x 512 slots x 16B
//                    slot = [u32 tag | fp16x2 pairA | fp16x2 pairB | u32 tagback]
//   [65536, +32MB) : hidden, T x HID bf16
#define WS_HBUF_OFF 4096
#define WS_HIDDEN_OFF 65536

__global__ void gru_init_kernel(u64* h_pair) {
  h_pair[blockIdx.x * 256 + threadIdx.x] = 0ull;  // 2048 u64
}

__device__ __forceinline__ half2v bc_h2(unsigned u) {
  union { unsigned u; half2v h; } c;
  c.u = u;
  return c.h;
}
__device__ __forceinline__ unsigned pk_rn(float lo, float hi) {
  union { half2v h; unsigned u; } c;
  c.h[0] = (_Float16)lo;  // RNE
  c.h[1] = (_Float16)hi;
  return c.u;
}
__device__ __forceinline__ unsigned pk_rtz(float lo, float hi) {
  union { fp16x2 h; unsigned u; } c;
  c.h = __builtin_amdgcn_cvt_pkrtz(lo, hi);
  return c.u;
}
__device__ __forceinline__ float fdot2f(unsigned a, unsigned b, float c) {
#if __has_builtin(__builtin_amdgcn_fdot2)
  return __builtin_amdgcn_fdot2(bc_h2(a), bc_h2(b), c, false);
#else
  const half2v ha = bc_h2(a), hb = bc_h2(b);
  return c + (float)ha[0] * (float)hb[0] + (float)ha[1] * (float)hb[1];
#endif
}

// r14 = r9 (best: 21.5ms) + wi·x computed in-register DURING the h-poll wait.
// 128 blocks x 512 threads. Block w owns units w*16..+15; wave v owns units
// w*16+2v, +2v+1 (weight rows {i,H+i,2H+i} packed fp16, asm-pinned).
// Exchange (r9 exactly): 512 seqlock slots of 16B; thread tid polls slot tid
// (2 u64 loads/round); producer publishes all 16 units as ONE coalesced 64B
// burst (threads 0..7) after sync2 — r13 proved scattered same-line 8B
// stores cost +1.1us/step (MALL line serialization), so the burst stays.
// x never touches LDS: each lane loads its own float4 of ys and computes all
// 6 wi·x partial dots while the poll waits on stale tags.
__global__ __launch_bounds__(NTHR, 2) void gru_scan_kernel(
    const float* __restrict__ ys, const float* __restrict__ wi,
    const float* __restrict__ wh, const float* __restrict__ b,
    const float* __restrict__ bn, __hip_bfloat16* __restrict__ hidden,
    u64* h_pair) {
  const int w = blockIdx.x;
  const int tid = threadIdx.x;
  const int wave = tid >> 6;
  const int lane = tid & 63;

  __shared__ __align__(16) unsigned hq_lds[2][HID / 2];  // fp16x2 pairs, 2x4KB
  __shared__ unsigned pair_lds[2][8];                    // per-wave fp16x2

  // ---- one-time: stage 6 rows/wave of wh,wi as packed fp16 in VGPRs ----
  unsigned whp[6][16];
  unsigned wip[6][4];
#pragma unroll
  for (int r = 0; r < 6; ++r) {
    const int g = r >> 1, e = r & 1;
    const size_t R = (size_t)(g * HID + w * 16 + 2 * wave + e);
#pragma unroll
    for (int m = 0; m < 8; ++m) {
      const float4 q =
          *reinterpret_cast<const float4*>(wh + R * HID + m * 256 + lane * 4);
      whp[r][2 * m] = pk_rn(q.x, q.y);
      whp[r][2 * m + 1] = pk_rn(q.z, q.w);
    }
#pragma unroll
    for (int p = 0; p < 2; ++p) {
      const float4 q =
          *reinterpret_cast<const float4*>(wi + R * 512 + p * 256 + lane * 4);
      wip[r][2 * p] = pk_rn(q.x, q.y);
      wip[r][2 * p + 1] = pk_rn(q.z, q.w);
    }
  }
#pragma unroll
  for (int r = 0; r < 6; ++r) {
#pragma unroll
    for (int m = 0; m < 16; ++m) asm volatile("" : "+v"(whp[r][m]));
#pragma unroll
    for (int p = 0; p < 4; ++p) asm volatile("" : "+v"(wip[r][p]));
  }

  // Gate constants for this wave's unit (lane&1 selects which of the pair).
  const int iu = w * 16 + 2 * wave + (lane & 1);
  const float b_r = b[iu];
  const float b_z = b[HID + iu];
  const float b_n = b[2 * HID + iu];
  const float bn_v = bn[iu];

  float h_own = 0.f;  // lanes 0,1: f32 recurrence state of own unit

#pragma unroll 1
  for (int s = 0; s < T_STEPS; ++s) {
    const int buf = s & 1;
    const u64* hp = h_pair + buf * (2 * NSLOT);  // 1024 u64 per buffer
    u64* hp_next = h_pair + (buf ^ 1) * (2 * NSLOT);
    const unsigned tag = (unsigned)s;

    // ---- issue poll loads FIRST (longest latency) ----
    u64 v0 = __hip_atomic_load(hp + 2 * tid, __ATOMIC_RELAXED,
                               __HIP_MEMORY_SCOPE_AGENT);
    u64 v1 = __hip_atomic_load(hp + 2 * tid + 1, __ATOMIC_RELAXED,
                               __HIP_MEMORY_SCOPE_AGENT);

    // ---- h-independent work, overlapped with the poll wait ----
    // lane's own x fragment: obs[4*lane .. 4*lane+3] (row L2-hot after wave 0)
    const float4 yv =
        *reinterpret_cast<const float4*>(ys + (size_t)s * OBS + lane * 4);
    const bool k0 = (yv.x == yv.x), k1 = (yv.y == yv.y), k2 = (yv.z == yv.z),
               k3 = (yv.w == yv.w);
    unsigned xq[4];
    xq[0] = pk_rtz(k0 ? yv.x : 0.f, k1 ? yv.y : 0.f);
    xq[1] = pk_rtz(k2 ? yv.z : 0.f, k3 ? yv.w : 0.f);
    xq[2] = pk_rtz(k0 ? 1.f : 0.f, k1 ? 1.f : 0.f);
    xq[3] = pk_rtz(k2 ? 1.f : 0.f, k3 ? 1.f : 0.f);

    // 6 wi·x partial dots (seed values for the post-sync accumulators)
    float pR[2], pZ[2], pIN[2];
#pragma unroll
    for (int e = 0; e < 2; ++e) {
      float ar = 0.f, az = 0.f, ain = 0.f;
#pragma unroll
      for (int p = 0; p < 4; ++p) {
        ar = fdot2f(wip[e][p], xq[p], ar);
        az = fdot2f(wip[2 + e][p], xq[p], az);
        ain = fdot2f(wip[4 + e][p], xq[p], ain);
      }
      pR[e] = ar;
      pZ[e] = az;
      pIN[e] = ain;
    }

    // ---- finish poll (seqlock tags at both ends of the 16B slot) ----
    while ((unsigned)(v0 >> 32) != tag || (unsigned)v1 != tag) {
      __builtin_amdgcn_s_sleep(1);
      v0 = __hip_atomic_load(hp + 2 * tid, __ATOMIC_RELAXED,
                             __HIP_MEMORY_SCOPE_AGENT);
      v1 = __hip_atomic_load(hp + 2 * tid + 1, __ATOMIC_RELAXED,
                             __HIP_MEMORY_SCOPE_AGENT);
    }

    // ---- stage: slot tid covers units 4*tid..+3 = pairs 2*tid, 2*tid+1 ----
    hq_lds[buf][2 * tid] = (unsigned)v0;              // pairA
    hq_lds[buf][2 * tid + 1] = (unsigned)(v1 >> 32);  // pairB
    __syncthreads();  // sync1: all 512 slots fresh + staged

    // ---- h fragments straight from LDS ----
    unsigned hq[16];
#pragma unroll
    for (int m = 0; m < 8; ++m) {
      const uint2 q =
          *reinterpret_cast<const uint2*>(&hq_lds[buf][m * 128 + lane * 2]);
      hq[2 * m] = q.x;
      hq[2 * m + 1] = q.y;
    }

    // ---- 8 dot accumulators, seeded with the wi·x partials ----
    float a[8];
#pragma unroll
    for (int e = 0; e < 2; ++e) {
      float ar = pR[e], az = pZ[e], ahn = 0.f;
      const int r0 = e, r1 = 2 + e, r2 = 4 + e;
#pragma unroll
      for (int m = 0; m < 16; ++m) {
        ar = fdot2f(whp[r0][m], hq[m], ar);
        az = fdot2f(whp[r1][m], hq[m], az);
        ahn = fdot2f(whp[r2][m], hq[m], ahn);
      }
      a[4 * e] = ar;
      a[4 * e + 1] = az;
      a[4 * e + 2] = ahn;
      a[4 * e + 3] = pIN[e];
    }

    // ---- combining butterfly: all 8 sums in 10 shuffles ----
#pragma unroll
    for (int j = 0; j < 4; ++j) {
      const bool sel = (lane & 1) != 0;
      const float keep = sel ? a[j + 4] : a[j];
      const float send = sel ? a[j] : a[j + 4];
      a[j] = keep + __shfl_xor(send, 1, 64);
    }
#pragma unroll
    for (int j = 0; j < 2; ++j) {
      const bool sel = (lane & 2) != 0;
      const float keep = sel ? a[j + 2] : a[j];
      const float send = sel ? a[j] : a[j + 2];
      a[j] = keep + __shfl_xor(send, 2, 64);
    }
    {
      const bool sel = (lane & 4) != 0;
      const float keep = sel ? a[1] : a[0];
      const float send = sel ? a[0] : a[1];
      a[0] = keep + __shfl_xor(send, 4, 64);
    }
    float redv = a[0];
    redv += __shfl_xor(redv, 8, 64);
    redv += __shfl_xor(redv, 16, 64);
    redv += __shfl_xor(redv, 32, 64);

    // Component c at lane rev3(c): r_e@lane e, z_e@4+e, hn_e@2+e, in_e@6+e.
    const int e = lane & 1;
    const float d_r = __shfl(redv, e, 64);
    const float d_z = __shfl(redv, 4 + e, 64);
    const float d_hn = __shfl(redv, 2 + e, 64);
    const float d_in = __shfl(redv, 6 + e, 64);

    // ---- gate math on all lanes (only lanes 0,1 hold valid state) ----
    const float rg = 1.f / (1.f + expf(-(d_r + b_r)));
    const float zg = 1.f / (1.f + expf(-(d_z + b_z)));
    const float ng = tanhf(d_in + b_n + rg * (d_hn + bn_v));
    const float hnew = ng + zg * (h_own - ng);
    h_own = hnew;  // garbage on lanes>=2, never consumed

    const float h1 = __shfl(hnew, 1, 64);
    if (lane == 0) {
      pair_lds[buf][wave] = pk_rtz(hnew, h1);
      // bf16 pair for the output head (off the critical path)
      const unsigned bf =
          ((unsigned)__bfloat16_as_ushort(__float2bfloat16(h1)) << 16) |
          (unsigned)__bfloat16_as_ushort(__float2bfloat16(hnew));
      *reinterpret_cast<unsigned*>(
          &hidden[(size_t)s * HID + w * 16 + 2 * wave]) = bf;
    }
    __syncthreads();  // sync2: all 8 wave-pairs in pair_lds

    // ---- aggregated publish: ONE 64B burst (8 lanes x u64, seqlock) ----
    if (tid < 8) {
      const int q = tid >> 1;
      u64 pv;
      if ((tid & 1) == 0)  // {tag, pairA}
        pv = ((u64)(tag + 1) << 32) | (u64)pair_lds[buf][2 * q];
      else  // {pairB, tagback}
        pv = ((u64)pair_lds[buf][2 * q + 1] << 32) | (u64)(tag + 1);
      __hip_atomic_store(hp_next + w * 8 + tid, pv, __ATOMIC_RELAXED,
                         __HIP_MEMORY_SCOPE_AGENT);
    }
    // No end-of-step barrier: LDS double-buffered by parity; same-parity
    // reuse is separated by two block-wide sync1s.
  }
}

// out[t][o] = bl[o] + sum_k hidden[t][k] * Wl[o][k]
// 64x64 tile, 256 threads, 4x4 micro-tile, BK=16.
__global__ __launch_bounds__(256) void out_gemm_kernel(
    const __hip_bfloat16* __restrict__ hidden, const float* __restrict__ Wl,
    const float* __restrict__ bl, float* __restrict__ out) {
  __shared__ float As[16][68];
  __shared__ float Bs[16][68];
  const int tid = threadIdx.x;
  const int bt = blockIdx.x * 64;
  const int bo = blockIdx.y * 64;
  const int tx = tid & 15;
  const int ty = tid >> 4;
  const int tA = tid >> 2;
  const int kq = (tid & 3) << 2;
  const unsigned short* hidu = reinterpret_cast<const unsigned short*>(hidden);

  float acc[4][4];
#pragma unroll
  for (int i = 0; i < 4; ++i)
#pragma unroll
    for (int j = 0; j < 4; ++j) acc[i][j] = 0.f;

  for (int k0 = 0; k0 < HID; k0 += 16) {
    const ushort4 av = *reinterpret_cast<const ushort4*>(
        hidu + (size_t)(bt + tA) * HID + k0 + kq);
    As[kq + 0][tA] = __uint_as_float((unsigned)av.x << 16);
    As[kq + 1][tA] = __uint_as_float((unsigned)av.y << 16);
    As[kq + 2][tA] = __uint_as_float((unsigned)av.z << 16);
    As[kq + 3][tA] = __uint_as_float((unsigned)av.w << 16);
    const float4 bv = *reinterpret_cast<const float4*>(
        Wl + (size_t)(bo + tA) * HID + k0 + kq);
    Bs[kq + 0][tA] = bv.x;
    Bs[kq + 1][tA] = bv.y;
    Bs[kq + 2][tA] = bv.z;
    Bs[kq + 3][tA] = bv.w;
    __syncthreads();
#pragma unroll
    for (int k = 0; k < 16; ++k) {
      const float4 a = *reinterpret_cast<const float4*>(&As[k][ty << 2]);
      const float4 bq = *reinterpret_cast<const float4*>(&Bs[k][tx << 2]);
      const float a4[4] = {a.x, a.y, a.z, a.w};
      const float b4[4] = {bq.x, bq.y, bq.z, bq.w};
#pragma unroll
      for (int i = 0; i < 4; ++i)
#pragma unroll
        for (int j = 0; j < 4; ++j) acc[i][j] += a4[i] * b4[j];
    }
    __syncthreads();
  }
#pragma unroll
  for (int i = 0; i < 4; ++i) {
    const int t = bt + (ty << 2) + i;
#pragma unroll
    for (int j = 0; j < 4; ++j) {
      const int o = bo + (tx << 2) + j;
      out[(size_t)t * NOUT + o] = acc[i][j] + bl[o];
    }
  }
}

extern "C" void kernel_launch(void* const* d_in, const int* in_sizes, int n_in,
                              void* d_out, int out_size, void* d_ws,
                              size_t ws_size, hipStream_t stream) {
  (void)in_sizes;
  (void)n_in;
  (void)out_size;
  (void)ws_size;
  // setup_inputs order: ts, ys, wi, wh, b, bn, Wl, bl (all f32)
  const float* ys = (const float*)d_in[1];
  const float* wi = (const float*)d_in[2];
  const float* wh = (const float*)d_in[3];
  const float* b = (const float*)d_in[4];
  const float* bn = (const float*)d_in[5];
  const float* Wl = (const float*)d_in[6];
  const float* bl = (const float*)d_in[7];
  float* out = (float*)d_out;

  u64* h_pair = (u64*)((char*)d_ws + WS_HBUF_OFF);
  __hip_bfloat16* hidden = (__hip_bfloat16*)((char*)d_ws + WS_HIDDEN_OFF);

  gru_init_kernel<<<8, 256, 0, stream>>>(h_pair);

  gru_scan_kernel<<<dim3(NBLK), dim3(NTHR), 0, stream>>>(ys, wi, wh, b, bn,
                                                         hidden, h_pair);

  out_gemm_kernel<<<dim3(T_STEPS / 64, NOUT / 64), 256, 0, stream>>>(
      hidden, Wl, bl, out);
}